// Round 10
// baseline (190.696 us; speedup 1.0000x reference)
//
#include <hip/hip_runtime.h>

typedef __attribute__((ext_vector_type(8))) short short8;   // 8 bf16 (4 VGPR)
typedef __attribute__((ext_vector_type(4))) float f32x4;    // MFMA C/D
typedef __attribute__((ext_vector_type(4))) int int4v;

#define CHUNK 256
#define NBINS 32
#define NCLS  10
#define NREP  16

__device__ __forceinline__ float asf(unsigned int u) { return __builtin_bit_cast(float, u); }
__device__ __forceinline__ unsigned int asu(float f) { return __builtin_bit_cast(unsigned int, f); }

__global__ __launch_bounds__(128) void dvh_main(
    const float* __restrict__ pred, const float* __restrict__ targ,
    const float* __restrict__ mask, float* __restrict__ gD, float* __restrict__ gN,
    int chunksPerN)
{
    __shared__ float2 sE[CHUNK];                 // (Ep,Et) per voxel, 2 KB
    __shared__ unsigned short mT[16 * CHUNK];    // bf16 masks [cls][vox] swizzled, 8 KB

    const int tid  = threadIdx.x;
    const int lane = tid & 63;
    const int w    = tid >> 6;       // wave 0..1
    const int n15  = lane & 15;      // MFMA row/col index
    const int g    = lane >> 4;      // k-group 0..3

    const int chunk = blockIdx.x;
    const size_t vbase = (size_t)chunk * CHUNK;

    // ---- issue ALL global loads first ----
    float2 p = ((const float2*)(pred + vbase))[tid];
    float2 t = ((const float2*)(targ + vbase))[tid];
    uint4 mv[5];
    {
        const uint4* m4g = (const uint4*)(mask + vbase * NCLS);
        #pragma unroll
        for (int k = 0; k < 5; ++k) mv[k] = m4g[k * 128 + tid];
    }

    // zero junk class rows 10..15 (768 u32 words, 128 threads x 6)
    {
        unsigned int* z = (unsigned int*)&mT[10 * CHUNK];
        #pragma unroll
        for (int i = 0; i < 6; ++i) z[i * 128 + tid] = 0;
    }

    const float K1 = __expf((float)n15);        // e^bin, bins 0..15
    const float K2 = K1 * 8886110.5f;           // * e^16 -> bins 16..31

    // ---- stage doses: exp once per voxel ----
    *(float4*)&sE[2 * tid] = make_float4(__expf(-32.f * p.x), __expf(-32.f * t.x),
                                         __expf(-32.f * p.y), __expf(-32.f * t.y));
    // ---- stage masks: 0/1 f32 -> bf16 (top 16 bits), swizzled transpose ----
    #pragma unroll
    for (int k = 0; k < 5; ++k) {
        int f = (k * 128 + tid) * 4;
        unsigned int e[4] = {mv[k].x, mv[k].y, mv[k].z, mv[k].w};
        #pragma unroll
        for (int q = 0; q < 4; ++q) {
            int v = (f + q) / 10;
            int c = (f + q) - v * 10;
            mT[c * CHUNK + (((v >> 3) ^ (c & 7)) << 3) + (v & 7)] =
                (unsigned short)(e[q] >> 16);
        }
    }
    __syncthreads();

    f32x4 accH1 = {0,0,0,0}, accL1 = {0,0,0,0};  // bins 0-15 hi/lo
    f32x4 accH2 = {0,0,0,0}, accL2 = {0,0,0,0};  // bins 16-31 hi/lo
    f32x4 cnt   = {0,0,0,0};                     // voxel counts
    short8 ones;
    #pragma unroll
    for (int i = 0; i < 8; ++i) ones[i] = (short)0x3F80;   // bf16 1.0

    #pragma unroll
    for (int st = 0; st < 4; ++st) {
        const int vb = (w * 4 + st) * 32;    // this wave's 32-voxel K-block
        const int v0 = vb + g * 8;           // this lane's 8 voxels
        short8 fb = *(const short8*)&mT[n15 * CHUNK + (((v0 >> 3) ^ (n15 & 7)) << 3)];
        const float4* e4 = (const float4*)&sE[v0];

        int uh1[4], ul1[4], uh2[4], ul2[4];
        #pragma unroll
        for (int j = 0; j < 4; ++j) {
            float4 q = e4[j];                 // vox a: (q.x,q.y)  vox b: (q.z,q.w)
            float dea = q.y - q.x, deb = q.w - q.z;
            // ---- K1, shared rcp across the voxel pair ----
            {
                float pra = fmaf(q.x, K1, 1.f) * fmaf(q.y, K1, 1.f);
                float prb = fmaf(q.z, K1, 1.f) * fmaf(q.w, K1, 1.f);
                float rD  = __builtin_amdgcn_rcpf(pra * prb);
                float sa  = (dea * K1) * (prb * rD);
                float sb  = (deb * K1) * (pra * rD);
                unsigned ua = asu(sa), ub = asu(sb);
                uh1[j] = (int)((ua >> 16) | (ub & 0xffff0000u));
                float la = sa - asf(ua & 0xffff0000u);
                float lb = sb - asf(ub & 0xffff0000u);
                unsigned lo1;
                asm("v_cvt_pk_bf16_f32 %0, %1, %2" : "=v"(lo1) : "v"(la), "v"(lb));
                ul1[j] = (int)lo1;
            }
            // ---- K2 ----
            {
                float pra = fmaf(q.x, K2, 1.f) * fmaf(q.y, K2, 1.f);
                float prb = fmaf(q.z, K2, 1.f) * fmaf(q.w, K2, 1.f);
                float rD  = __builtin_amdgcn_rcpf(pra * prb);
                float sa  = (dea * K2) * (prb * rD);
                float sb  = (deb * K2) * (pra * rD);
                unsigned ua = asu(sa), ub = asu(sb);
                uh2[j] = (int)((ua >> 16) | (ub & 0xffff0000u));
                float la = sa - asf(ua & 0xffff0000u);
                float lb = sb - asf(ub & 0xffff0000u);
                unsigned lo2;
                asm("v_cvt_pk_bf16_f32 %0, %1, %2" : "=v"(lo2) : "v"(la), "v"(lb));
                ul2[j] = (int)lo2;
            }
        }
        int4v th1 = {uh1[0], uh1[1], uh1[2], uh1[3]};
        int4v tl1 = {ul1[0], ul1[1], ul1[2], ul1[3]};
        int4v th2 = {uh2[0], uh2[1], uh2[2], uh2[3]};
        int4v tl2 = {ul2[0], ul2[1], ul2[2], ul2[3]};
        short8 A1h = __builtin_bit_cast(short8, th1);
        short8 A1l = __builtin_bit_cast(short8, tl1);
        short8 A2h = __builtin_bit_cast(short8, th2);
        short8 A2l = __builtin_bit_cast(short8, tl2);

        accH1 = __builtin_amdgcn_mfma_f32_16x16x32_bf16(A1h, fb, accH1, 0, 0, 0);
        accL1 = __builtin_amdgcn_mfma_f32_16x16x32_bf16(A1l, fb, accL1, 0, 0, 0);
        accH2 = __builtin_amdgcn_mfma_f32_16x16x32_bf16(A2h, fb, accH2, 0, 0, 0);
        accL2 = __builtin_amdgcn_mfma_f32_16x16x32_bf16(A2l, fb, accL2, 0, 0, 0);
        cnt   = __builtin_amdgcn_mfma_f32_16x16x32_bf16(ones, fb, cnt,   0, 0, 0);
    }

    // ---- epilogue: direct replicated atomics (no LDS reduce, no barrier) ----
    const int rep = chunk & (NREP - 1);
    float* gDr = gD + rep * (NBINS * NCLS);
    float* gNr = gN + rep * (2 * NCLS);
    const int nsel = (chunk < chunksPerN) ? 0 : 1;

    f32x4 d1 = accH1 + accL1;
    f32x4 d2 = accH2 + accL2;
    if (n15 < NCLS) {
        #pragma unroll
        for (int r = 0; r < 4; ++r) {
            int b1 = g * 4 + r;                  // C/D: row=(lane>>4)*4+reg, col=lane&15
            atomicAdd(&gDr[b1 * NCLS + n15],        d1[r]);
            atomicAdd(&gDr[(16 + b1) * NCLS + n15], d2[r]);
        }
    }
    if (lane < NCLS) atomicAdd(&gNr[nsel * NCLS + lane], cnt[0]);  // row 0 of count tile
}

__global__ __launch_bounds__(512) void dvh_final(
    const float* __restrict__ gD, const float* __restrict__ gN, float* __restrict__ out)
{
    __shared__ float red[512];
    int t = threadIdx.x;
    float v = 0.f;
    if (t < NBINS * NCLS) {
        int c = t % NCLS;
        float nv0 = 1.f, nv1 = 1.f, d = 0.f;
        #pragma unroll
        for (int r = 0; r < NREP; ++r) {
            d   += gD[r * (NBINS * NCLS) + t];
            nv0 += gN[r * (2 * NCLS) + c];
            nv1 += gN[r * (2 * NCLS) + NCLS + c];
        }
        float w = 1.f / (nv0 * nv0) + 1.f / (nv1 * nv1);
        v = d * d * w;
    }
    red[t] = v;
    __syncthreads();
    for (int s = 256; s > 0; s >>= 1) {
        if (t < s) red[t] += red[t + s];
        __syncthreads();
    }
    if (t == 0) out[0] = red[0] * (1.f / 1280.f);
}

extern "C" void kernel_launch(void* const* d_in, const int* in_sizes, int n_in,
                              void* d_out, int out_size, void* d_ws, size_t ws_size,
                              hipStream_t stream) {
    const float* pred = (const float*)d_in[0];
    const float* targ = (const float*)d_in[1];
    const float* mask = (const float*)d_in[2];
    float* gD = (float*)d_ws;                                    // NREP x 320 floats
    float* gN = (float*)((char*)d_ws + NREP * NBINS * NCLS * 4); // NREP x 20 floats

    hipMemsetAsync(d_ws, 0, NREP * (NBINS * NCLS + 2 * NCLS) * 4, stream);

    int totalVox    = in_sizes[0];           // N*V = 4194304
    int chunksTotal = totalVox / CHUNK;      // 16384
    int chunksPerN  = chunksTotal / 2;       // 8192

    dvh_main<<<chunksTotal, 128, 0, stream>>>(pred, targ, mask, gD, gN, chunksPerN);
    dvh_final<<<1, 512, 0, stream>>>(gD, gN, (float*)d_out);
}

// Round 11
// 77.577 us; speedup vs baseline: 2.4581x; 2.4581x over previous
//
#include <hip/hip_runtime.h>

typedef __attribute__((ext_vector_type(8))) short short8;   // 8 bf16 (4 VGPR)
typedef __attribute__((ext_vector_type(4))) float f32x4;    // MFMA C/D
typedef __attribute__((ext_vector_type(4))) int int4v;

#define CHUNK 512
#define NBINS 32
#define NCLS  10
#define NREP  64

__device__ __forceinline__ float asf(unsigned int u) { return __builtin_bit_cast(float, u); }
__device__ __forceinline__ unsigned int asu(float f) { return __builtin_bit_cast(unsigned int, f); }

__global__ __launch_bounds__(256) void dvh_main(
    const float* __restrict__ pred, const float* __restrict__ targ,
    const float* __restrict__ mask, float* __restrict__ gD, float* __restrict__ gN,
    int chunksPerN)
{
    __shared__ float2 sE[CHUNK];                 // (Ep,Et) per voxel, 4 KB
    __shared__ unsigned short mT[16 * 512];      // bf16 masks [cls][vox] swizzled, 16 KB

    const int tid  = threadIdx.x;
    const int lane = tid & 63;
    const int w    = tid >> 6;       // wave 0..3
    const int n15  = lane & 15;      // MFMA row/col index
    const int g    = lane >> 4;      // k-group 0..3

    const int chunk = blockIdx.x;
    const size_t vbase = (size_t)chunk * CHUNK;

    // ---- issue ALL global loads first ----
    float2 p = ((const float2*)(pred + vbase))[tid];
    float2 t = ((const float2*)(targ + vbase))[tid];
    uint4 mv[5];
    {
        const uint4* m4g = (const uint4*)(mask + vbase * NCLS);
        #pragma unroll
        for (int k = 0; k < 5; ++k) mv[k] = m4g[k * 256 + tid];
    }

    // zero junk class rows 10..15 (read by B-frags, never staged)
    #pragma unroll
    for (int i = 0; i < 12; ++i) mT[10 * 512 + i * 256 + tid] = 0;

    const float K1 = __expf((float)n15);        // e^bin, bins 0..15
    const float K2 = K1 * 8886110.5f;           // * e^16 -> bins 16..31

    // ---- stage doses: exp once per voxel ----
    *(float4*)&sE[2 * tid] = make_float4(__expf(-32.f * p.x), __expf(-32.f * t.x),
                                         __expf(-32.f * p.y), __expf(-32.f * t.y));
    // ---- stage masks: 0/1 f32 -> bf16 (top 16 bits), swizzled transpose ----
    #pragma unroll
    for (int k = 0; k < 5; ++k) {
        int f = (k * 256 + tid) * 4;
        unsigned int e[4] = {mv[k].x, mv[k].y, mv[k].z, mv[k].w};
        #pragma unroll
        for (int q = 0; q < 4; ++q) {
            int v = (f + q) / 10;
            int c = (f + q) - v * 10;
            mT[c * 512 + (((v >> 3) ^ (c & 7)) << 3) + (v & 7)] =
                (unsigned short)(e[q] >> 16);
        }
    }
    __syncthreads();

    f32x4 accH1 = {0,0,0,0}, accL1 = {0,0,0,0};  // bins 0-15 hi/lo
    f32x4 accH2 = {0,0,0,0}, accL2 = {0,0,0,0};  // bins 16-31 hi/lo
    f32x4 cnt   = {0,0,0,0};                     // voxel counts
    short8 ones;
    #pragma unroll
    for (int i = 0; i < 8; ++i) ones[i] = (short)0x3F80;   // bf16 1.0

    #pragma unroll
    for (int st = 0; st < 4; ++st) {
        const int vb = (w * 4 + st) * 32;    // this wave's 32-voxel K-block
        const int v0 = vb + g * 8;           // this lane's 8 voxels
        short8 fb = *(const short8*)&mT[n15 * 512 + (((v0 >> 3) ^ (n15 & 7)) << 3)];
        const float4* e4 = (const float4*)&sE[v0];

        int uh1[4], ul1[4], uh2[4], ul2[4];
        #pragma unroll
        for (int j = 0; j < 4; ++j) {
            float4 q = e4[j];                 // vox a: (q.x,q.y)  vox b: (q.z,q.w)
            float dea = q.y - q.x, deb = q.w - q.z;
            {   // ---- K1, shared rcp across the voxel pair ----
                float pra = fmaf(q.x, K1, 1.f) * fmaf(q.y, K1, 1.f);
                float prb = fmaf(q.z, K1, 1.f) * fmaf(q.w, K1, 1.f);
                float rD  = __builtin_amdgcn_rcpf(pra * prb);
                float sa  = (dea * K1) * (prb * rD);
                float sb  = (deb * K1) * (pra * rD);
                unsigned ua = asu(sa), ub = asu(sb);
                uh1[j] = (int)((ua >> 16) | (ub & 0xffff0000u));
                float la = sa - asf(ua & 0xffff0000u);
                float lb = sb - asf(ub & 0xffff0000u);
                unsigned lo1;
                asm("v_cvt_pk_bf16_f32 %0, %1, %2" : "=v"(lo1) : "v"(la), "v"(lb));
                ul1[j] = (int)lo1;
            }
            {   // ---- K2 ----
                float pra = fmaf(q.x, K2, 1.f) * fmaf(q.y, K2, 1.f);
                float prb = fmaf(q.z, K2, 1.f) * fmaf(q.w, K2, 1.f);
                float rD  = __builtin_amdgcn_rcpf(pra * prb);
                float sa  = (dea * K2) * (prb * rD);
                float sb  = (deb * K2) * (pra * rD);
                unsigned ua = asu(sa), ub = asu(sb);
                uh2[j] = (int)((ua >> 16) | (ub & 0xffff0000u));
                float la = sa - asf(ua & 0xffff0000u);
                float lb = sb - asf(ub & 0xffff0000u);
                unsigned lo2;
                asm("v_cvt_pk_bf16_f32 %0, %1, %2" : "=v"(lo2) : "v"(la), "v"(lb));
                ul2[j] = (int)lo2;
            }
        }
        int4v th1 = {uh1[0], uh1[1], uh1[2], uh1[3]};
        int4v tl1 = {ul1[0], ul1[1], ul1[2], ul1[3]};
        int4v th2 = {uh2[0], uh2[1], uh2[2], uh2[3]};
        int4v tl2 = {ul2[0], ul2[1], ul2[2], ul2[3]};
        short8 A1h = __builtin_bit_cast(short8, th1);
        short8 A1l = __builtin_bit_cast(short8, tl1);
        short8 A2h = __builtin_bit_cast(short8, th2);
        short8 A2l = __builtin_bit_cast(short8, tl2);

        accH1 = __builtin_amdgcn_mfma_f32_16x16x32_bf16(A1h, fb, accH1, 0, 0, 0);
        accL1 = __builtin_amdgcn_mfma_f32_16x16x32_bf16(A1l, fb, accL1, 0, 0, 0);
        accH2 = __builtin_amdgcn_mfma_f32_16x16x32_bf16(A2h, fb, accH2, 0, 0, 0);
        accL2 = __builtin_amdgcn_mfma_f32_16x16x32_bf16(A2l, fb, accL2, 0, 0, 0);
        cnt   = __builtin_amdgcn_mfma_f32_16x16x32_bf16(ones, fb, cnt,   0, 0, 0);
    }
    __syncthreads();                  // all waves done reading mT

    // ---- epilogue: block reduce via LDS (reuse mT), then replicated atomics ----
    float* red  = (float*)mT;        // [4 waves][32 bins][10 cls] = 1280 floats
    float* redN = red + 1280;        // [4 waves][10]

    f32x4 d1 = accH1 + accL1;
    f32x4 d2 = accH2 + accL2;
    if (n15 < NCLS) {
        #pragma unroll
        for (int r = 0; r < 4; ++r) {
            int b1 = g * 4 + r;                  // C/D: row=(lane>>4)*4+reg, col=lane&15
            red[(w * 32 + b1) * NCLS + n15]      = d1[r];
            red[(w * 32 + 16 + b1) * NCLS + n15] = d2[r];
        }
    }
    if (lane < NCLS) redN[w * NCLS + lane] = cnt[0];   // row 0 of count tile
    __syncthreads();

    const int rep = chunk & (NREP - 1);       // XCD-aligned (chunk%8 == XCD id)
    float* gDr = gD + rep * (NBINS * NCLS);
    float* gNr = gN + rep * (2 * NCLS);
    const int nsel = (chunk < chunksPerN) ? 0 : 1;

    for (int i = tid; i < NBINS * NCLS; i += 256) {
        float s = red[i] + red[320 + i] + red[640 + i] + red[960 + i];
        atomicAdd(&gDr[i], s);
    }
    if (tid < NCLS) {
        float s = redN[tid] + redN[10 + tid] + redN[20 + tid] + redN[30 + tid];
        atomicAdd(&gNr[nsel * NCLS + tid], s);
    }
}

__global__ __launch_bounds__(512) void dvh_final(
    const float* __restrict__ gD, const float* __restrict__ gN, float* __restrict__ out)
{
    __shared__ float red[512];
    int t = threadIdx.x;
    float v = 0.f;
    if (t < NBINS * NCLS) {
        int c = t % NCLS;
        float nv0 = 1.f, nv1 = 1.f, d = 0.f;
        for (int r = 0; r < NREP; ++r) {
            d   += gD[r * (NBINS * NCLS) + t];
            nv0 += gN[r * (2 * NCLS) + c];
            nv1 += gN[r * (2 * NCLS) + NCLS + c];
        }
        float w = 1.f / (nv0 * nv0) + 1.f / (nv1 * nv1);
        v = d * d * w;
    }
    red[t] = v;
    __syncthreads();
    for (int s = 256; s > 0; s >>= 1) {
        if (t < s) red[t] += red[t + s];
        __syncthreads();
    }
    if (t == 0) out[0] = red[0] * (1.f / 1280.f);
}

extern "C" void kernel_launch(void* const* d_in, const int* in_sizes, int n_in,
                              void* d_out, int out_size, void* d_ws, size_t ws_size,
                              hipStream_t stream) {
    const float* pred = (const float*)d_in[0];
    const float* targ = (const float*)d_in[1];
    const float* mask = (const float*)d_in[2];
    float* gD = (float*)d_ws;                                    // NREP x 320 floats
    float* gN = (float*)((char*)d_ws + NREP * NBINS * NCLS * 4); // NREP x 20 floats

    hipMemsetAsync(d_ws, 0, NREP * (NBINS * NCLS + 2 * NCLS) * 4, stream);

    int totalVox    = in_sizes[0];           // N*V = 4194304
    int chunksTotal = totalVox / CHUNK;      // 8192
    int chunksPerN  = chunksTotal / 2;       // 4096

    dvh_main<<<chunksTotal, 256, 0, stream>>>(pred, targ, mask, gD, gN, chunksPerN);
    dvh_final<<<1, 512, 0, stream>>>(gD, gN, (float*)d_out);
}

// Round 12
// 73.380 us; speedup vs baseline: 2.5988x; 1.0572x over previous
//
#include <hip/hip_runtime.h>

typedef __attribute__((ext_vector_type(8))) short short8;   // 8 bf16 (4 VGPR)
typedef __attribute__((ext_vector_type(4))) float f32x4;    // MFMA C/D
typedef __attribute__((ext_vector_type(4))) int int4v;

#define CHUNK 512
#define NBINS 32
#define NCLS  10
#define NREP  64

__device__ __forceinline__ float asf(unsigned int u) { return __builtin_bit_cast(float, u); }
__device__ __forceinline__ unsigned int asu(float f) { return __builtin_bit_cast(unsigned int, f); }

__global__ __launch_bounds__(256) void dvh_main(
    const float* __restrict__ pred, const float* __restrict__ targ,
    const float* __restrict__ mask, float* __restrict__ gD, float* __restrict__ gN,
    int chunksPerN)
{
    __shared__ float2 sE[CHUNK];                 // (Ep,Et) per voxel, 4 KB
    __shared__ unsigned short mT[16 * 512];      // bf16 masks [cls][vox] swizzled, 16 KB

    const int tid  = threadIdx.x;
    const int lane = tid & 63;
    const int w    = tid >> 6;       // wave 0..3
    const int n15  = lane & 15;      // MFMA row/col index
    const int g    = lane >> 4;      // k-group 0..3

    const int chunk = blockIdx.x;
    const size_t vbase = (size_t)chunk * CHUNK;

    // ---- issue ALL global loads first ----
    float2 p = ((const float2*)(pred + vbase))[tid];
    float2 t = ((const float2*)(targ + vbase))[tid];
    uint4 mv[5];
    {
        const uint4* m4g = (const uint4*)(mask + vbase * NCLS);
        #pragma unroll
        for (int k = 0; k < 5; ++k) mv[k] = m4g[k * 256 + tid];
    }

    // zero junk class rows 10..15 (read by B-frags, never staged)
    #pragma unroll
    for (int i = 0; i < 12; ++i) mT[10 * 512 + i * 256 + tid] = 0;

    const float K1 = __expf((float)n15);        // e^bin, bins 0..15
    const float K2 = K1 * 8886110.5f;           // * e^16 -> bins 16..31

    // ---- stage doses: exp once per voxel ----
    *(float4*)&sE[2 * tid] = make_float4(__expf(-32.f * p.x), __expf(-32.f * t.x),
                                         __expf(-32.f * p.y), __expf(-32.f * t.y));
    // ---- stage masks: 0/1 f32 -> bf16 (top 16 bits), swizzled transpose ----
    #pragma unroll
    for (int k = 0; k < 5; ++k) {
        int f = (k * 256 + tid) * 4;
        unsigned int e[4] = {mv[k].x, mv[k].y, mv[k].z, mv[k].w};
        #pragma unroll
        for (int q = 0; q < 4; ++q) {
            int v = (f + q) / 10;
            int c = (f + q) - v * 10;
            mT[c * 512 + (((v >> 3) ^ (c & 7)) << 3) + (v & 7)] =
                (unsigned short)(e[q] >> 16);
        }
    }
    __syncthreads();

    f32x4 accH1 = {0,0,0,0}, accL1 = {0,0,0,0};  // bins 0-15 hi/lo
    f32x4 accH2 = {0,0,0,0}, accL2 = {0,0,0,0};  // bins 16-31 hi/lo
    f32x4 cnt   = {0,0,0,0};                     // voxel counts
    short8 ones;
    #pragma unroll
    for (int i = 0; i < 8; ++i) ones[i] = (short)0x3F80;   // bf16 1.0

    #pragma unroll
    for (int st = 0; st < 4; ++st) {
        const int vb = (w * 4 + st) * 32;    // this wave's 32-voxel K-block
        const int v0 = vb + g * 8;           // this lane's 8 voxels
        short8 fb = *(const short8*)&mT[n15 * 512 + (((v0 >> 3) ^ (n15 & 7)) << 3)];
        const float4* e4 = (const float4*)&sE[v0];

        int uh1[4], ul1[4], uh2[4], ul2[4];
        #pragma unroll
        for (int j = 0; j < 4; ++j) {
            float4 q = e4[j];                 // vox a: (q.x,q.y)  vox b: (q.z,q.w)
            float dea = q.y - q.x, deb = q.w - q.z;
            {   // ---- K1, shared rcp across the voxel pair ----
                float pra = fmaf(q.x, K1, 1.f) * fmaf(q.y, K1, 1.f);
                float prb = fmaf(q.z, K1, 1.f) * fmaf(q.w, K1, 1.f);
                float rD  = __builtin_amdgcn_rcpf(pra * prb);
                float sa  = (dea * K1) * (prb * rD);
                float sb  = (deb * K1) * (pra * rD);
                unsigned ua = asu(sa), ub = asu(sb);
                uh1[j] = (int)((ua >> 16) | (ub & 0xffff0000u));
                float la = sa - asf(ua & 0xffff0000u);
                float lb = sb - asf(ub & 0xffff0000u);
                unsigned lo1;
                asm("v_cvt_pk_bf16_f32 %0, %1, %2" : "=v"(lo1) : "v"(la), "v"(lb));
                ul1[j] = (int)lo1;
            }
            {   // ---- K2 ----
                float pra = fmaf(q.x, K2, 1.f) * fmaf(q.y, K2, 1.f);
                float prb = fmaf(q.z, K2, 1.f) * fmaf(q.w, K2, 1.f);
                float rD  = __builtin_amdgcn_rcpf(pra * prb);
                float sa  = (dea * K2) * (prb * rD);
                float sb  = (deb * K2) * (pra * rD);
                unsigned ua = asu(sa), ub = asu(sb);
                uh2[j] = (int)((ua >> 16) | (ub & 0xffff0000u));
                float la = sa - asf(ua & 0xffff0000u);
                float lb = sb - asf(ub & 0xffff0000u);
                unsigned lo2;
                asm("v_cvt_pk_bf16_f32 %0, %1, %2" : "=v"(lo2) : "v"(la), "v"(lb));
                ul2[j] = (int)lo2;
            }
        }
        int4v th1 = {uh1[0], uh1[1], uh1[2], uh1[3]};
        int4v tl1 = {ul1[0], ul1[1], ul1[2], ul1[3]};
        int4v th2 = {uh2[0], uh2[1], uh2[2], uh2[3]};
        int4v tl2 = {ul2[0], ul2[1], ul2[2], ul2[3]};
        short8 A1h = __builtin_bit_cast(short8, th1);
        short8 A1l = __builtin_bit_cast(short8, tl1);
        short8 A2h = __builtin_bit_cast(short8, th2);
        short8 A2l = __builtin_bit_cast(short8, tl2);

        accH1 = __builtin_amdgcn_mfma_f32_16x16x32_bf16(A1h, fb, accH1, 0, 0, 0);
        accL1 = __builtin_amdgcn_mfma_f32_16x16x32_bf16(A1l, fb, accL1, 0, 0, 0);
        accH2 = __builtin_amdgcn_mfma_f32_16x16x32_bf16(A2h, fb, accH2, 0, 0, 0);
        accL2 = __builtin_amdgcn_mfma_f32_16x16x32_bf16(A2l, fb, accL2, 0, 0, 0);
        cnt   = __builtin_amdgcn_mfma_f32_16x16x32_bf16(ones, fb, cnt,   0, 0, 0);
    }
    __syncthreads();                  // all waves done reading mT

    // ---- epilogue: block reduce via LDS (reuse mT), then replicated atomics ----
    float* red  = (float*)mT;        // [4 waves][32 bins][10 cls] = 1280 floats
    float* redN = red + 1280;        // [4 waves][10]

    f32x4 d1 = accH1 + accL1;
    f32x4 d2 = accH2 + accL2;
    if (n15 < NCLS) {
        #pragma unroll
        for (int r = 0; r < 4; ++r) {
            int b1 = g * 4 + r;                  // C/D: row=(lane>>4)*4+reg, col=lane&15
            red[(w * 32 + b1) * NCLS + n15]      = d1[r];
            red[(w * 32 + 16 + b1) * NCLS + n15] = d2[r];
        }
    }
    if (lane < NCLS) redN[w * NCLS + lane] = cnt[0];   // row 0 of count tile
    __syncthreads();

    const int rep = chunk & (NREP - 1);       // XCD-aligned (chunk%8 == XCD id)
    float* gDr = gD + rep * (NBINS * NCLS);
    float* gNr = gN + rep * (2 * NCLS);
    const int nsel = (chunk < chunksPerN) ? 0 : 1;

    for (int i = tid; i < NBINS * NCLS; i += 256) {
        float s = red[i] + red[320 + i] + red[640 + i] + red[960 + i];
        atomicAdd(&gDr[i], s);
    }
    if (tid < NCLS) {
        float s = redN[tid] + redN[10 + tid] + redN[20 + tid] + redN[30 + tid];
        atomicAdd(&gNr[nsel * NCLS + tid], s);
    }
}

__global__ __launch_bounds__(512) void dvh_final(
    const float* __restrict__ gD, const float* __restrict__ gN, float* __restrict__ out)
{
    __shared__ float red[512];
    __shared__ float nvs[2 * NCLS];
    const int t = threadIdx.x;

    // rep-sum the 20 voxel counts (20 threads, 64 independent loads each, ILP)
    if (t < 2 * NCLS) {
        float s = 1.f;
        #pragma unroll
        for (int r = 0; r < NREP; ++r) s += gN[r * (2 * NCLS) + t];
        nvs[t] = s;
    }
    // rep-sum the 320 Delta entries (320 threads, 64 independent loads each)
    float d = 0.f;
    if (t < NBINS * NCLS) {
        #pragma unroll
        for (int r = 0; r < NREP; ++r) d += gD[r * (NBINS * NCLS) + t];
    }
    __syncthreads();

    float v = 0.f;
    if (t < NBINS * NCLS) {
        int c = t % NCLS;
        float nv0 = nvs[c], nv1 = nvs[NCLS + c];
        v = d * d * (1.f / (nv0 * nv0) + 1.f / (nv1 * nv1));
    }
    red[t] = v;
    __syncthreads();
    for (int s = 256; s > 0; s >>= 1) {
        if (t < s) red[t] += red[t + s];
        __syncthreads();
    }
    if (t == 0) out[0] = red[0] * (1.f / 1280.f);
}

extern "C" void kernel_launch(void* const* d_in, const int* in_sizes, int n_in,
                              void* d_out, int out_size, void* d_ws, size_t ws_size,
                              hipStream_t stream) {
    const float* pred = (const float*)d_in[0];
    const float* targ = (const float*)d_in[1];
    const float* mask = (const float*)d_in[2];
    float* gD = (float*)d_ws;                                    // NREP x 320 floats
    float* gN = (float*)((char*)d_ws + NREP * NBINS * NCLS * 4); // NREP x 20 floats

    hipMemsetAsync(d_ws, 0, NREP * (NBINS * NCLS + 2 * NCLS) * 4, stream);

    int totalVox    = in_sizes[0];           // N*V = 4194304
    int chunksTotal = totalVox / CHUNK;      // 8192
    int chunksPerN  = chunksTotal / 2;       // 4096

    dvh_main<<<chunksTotal, 256, 0, stream>>>(pred, targ, mask, gD, gN, chunksPerN);
    dvh_final<<<1, 512, 0, stream>>>(gD, gN, (float*)d_out);
}

// Round 13
// 59.546 us; speedup vs baseline: 3.2025x; 1.2323x over previous
//
#include <hip/hip_runtime.h>

typedef __attribute__((ext_vector_type(8))) short short8;   // 8 bf16 (4 VGPR)
typedef __attribute__((ext_vector_type(4))) float f32x4;    // MFMA C/D
typedef __attribute__((ext_vector_type(4))) int int4v;

#define CHUNK 512
#define NBINS 32
#define NCLS  10
#define NREP  8

__device__ __forceinline__ float asf(unsigned int u) { return __builtin_bit_cast(float, u); }
__device__ __forceinline__ unsigned int asu(float f) { return __builtin_bit_cast(unsigned int, f); }

__global__ __launch_bounds__(256) void dvh_main(
    const float* __restrict__ pred, const float* __restrict__ targ,
    const float* __restrict__ mask, float* __restrict__ gD, float* __restrict__ gN,
    int chunksPerN)
{
    __shared__ float2 sE[CHUNK];                 // (Ep,Et) per voxel, 4 KB
    __shared__ unsigned short mT[16 * 512];      // bf16 masks [cls][vox] swizzled, 16 KB

    const int tid  = threadIdx.x;
    const int lane = tid & 63;
    const int w    = tid >> 6;       // wave 0..3
    const int n15  = lane & 15;      // MFMA row/col index
    const int g    = lane >> 4;      // k-group 0..3

    const int chunk = blockIdx.x;
    const size_t vbase = (size_t)chunk * CHUNK;

    // ---- issue ALL global loads first (latency hides under setup) ----
    float2 p = ((const float2*)(pred + vbase))[tid];
    float2 t = ((const float2*)(targ + vbase))[tid];
    uint4 mv[5];
    {
        const uint4* m4g = (const uint4*)(mask + vbase * NCLS);
        #pragma unroll
        for (int k = 0; k < 5; ++k) mv[k] = m4g[k * 256 + tid];
    }

    // NOTE: mT class rows 10..15 intentionally left uninitialized. Garbage
    // there feeds only MFMA output columns n=10..15, which are never read
    // (MFMA columns are independent), so no zeroing pass is needed.

    const float K1 = __expf((float)n15);        // e^bin, bins 0..15
    const float K2 = K1 * 8886110.5f;           // * e^16 -> bins 16..31

    // ---- stage doses: exp once per voxel ----
    *(float4*)&sE[2 * tid] = make_float4(__expf(-32.f * p.x), __expf(-32.f * t.x),
                                         __expf(-32.f * p.y), __expf(-32.f * t.y));
    // ---- stage masks: 0/1 f32 -> bf16 (top 16 bits), swizzled transpose ----
    #pragma unroll
    for (int k = 0; k < 5; ++k) {
        int f = (k * 256 + tid) * 4;
        unsigned int e[4] = {mv[k].x, mv[k].y, mv[k].z, mv[k].w};
        #pragma unroll
        for (int q = 0; q < 4; ++q) {
            int v = (f + q) / 10;
            int c = (f + q) - v * 10;
            mT[c * 512 + (((v >> 3) ^ (c & 7)) << 3) + (v & 7)] =
                (unsigned short)(e[q] >> 16);
        }
    }
    __syncthreads();

    f32x4 accH1 = {0,0,0,0}, accL1 = {0,0,0,0};  // bins 0-15 hi/lo
    f32x4 accH2 = {0,0,0,0}, accL2 = {0,0,0,0};  // bins 16-31 hi/lo
    f32x4 cnt   = {0,0,0,0};                     // voxel counts
    short8 ones;
    #pragma unroll
    for (int i = 0; i < 8; ++i) ones[i] = (short)0x3F80;   // bf16 1.0

    #pragma unroll
    for (int st = 0; st < 4; ++st) {
        const int vb = (w * 4 + st) * 32;    // this wave's 32-voxel K-block
        const int v0 = vb + g * 8;           // this lane's 8 voxels
        short8 fb = *(const short8*)&mT[n15 * 512 + (((v0 >> 3) ^ (n15 & 7)) << 3)];
        const float4* e4 = (const float4*)&sE[v0];

        int uh1[4], ul1[4], uh2[4], ul2[4];
        #pragma unroll
        for (int j = 0; j < 4; ++j) {
            float4 q = e4[j];                 // vox a: (q.x,q.y)  vox b: (q.z,q.w)
            float dea = q.y - q.x, deb = q.w - q.z;
            float pa = fmaf(q.x, K1, 1.f) * fmaf(q.y, K1, 1.f);
            float pb = fmaf(q.z, K1, 1.f) * fmaf(q.w, K1, 1.f);
            float sa = dea * K1 * __builtin_amdgcn_rcpf(pa);
            float sb = deb * K1 * __builtin_amdgcn_rcpf(pb);
            unsigned ua = asu(sa), ub = asu(sb);
            uh1[j] = (int)((ua >> 16) | (ub & 0xffff0000u));
            float la = sa - asf(ua & 0xffff0000u);
            float lb = sb - asf(ub & 0xffff0000u);
            unsigned lo1;
            asm("v_cvt_pk_bf16_f32 %0, %1, %2" : "=v"(lo1) : "v"(la), "v"(lb));
            ul1[j] = (int)lo1;
            float pc = fmaf(q.x, K2, 1.f) * fmaf(q.y, K2, 1.f);
            float pd = fmaf(q.z, K2, 1.f) * fmaf(q.w, K2, 1.f);
            float sc = dea * K2 * __builtin_amdgcn_rcpf(pc);
            float sd = deb * K2 * __builtin_amdgcn_rcpf(pd);
            unsigned uc = asu(sc), ud = asu(sd);
            uh2[j] = (int)((uc >> 16) | (ud & 0xffff0000u));
            float lc = sc - asf(uc & 0xffff0000u);
            float ld = sd - asf(ud & 0xffff0000u);
            unsigned lo2;
            asm("v_cvt_pk_bf16_f32 %0, %1, %2" : "=v"(lo2) : "v"(lc), "v"(ld));
            ul2[j] = (int)lo2;
        }
        int4v th1 = {uh1[0], uh1[1], uh1[2], uh1[3]};
        int4v tl1 = {ul1[0], ul1[1], ul1[2], ul1[3]};
        int4v th2 = {uh2[0], uh2[1], uh2[2], uh2[3]};
        int4v tl2 = {ul2[0], ul2[1], ul2[2], ul2[3]};
        short8 A1h = __builtin_bit_cast(short8, th1);
        short8 A1l = __builtin_bit_cast(short8, tl1);
        short8 A2h = __builtin_bit_cast(short8, th2);
        short8 A2l = __builtin_bit_cast(short8, tl2);

        accH1 = __builtin_amdgcn_mfma_f32_16x16x32_bf16(A1h, fb, accH1, 0, 0, 0);
        accL1 = __builtin_amdgcn_mfma_f32_16x16x32_bf16(A1l, fb, accL1, 0, 0, 0);
        accH2 = __builtin_amdgcn_mfma_f32_16x16x32_bf16(A2h, fb, accH2, 0, 0, 0);
        accL2 = __builtin_amdgcn_mfma_f32_16x16x32_bf16(A2l, fb, accL2, 0, 0, 0);
        cnt   = __builtin_amdgcn_mfma_f32_16x16x32_bf16(ones, fb, cnt,   0, 0, 0);
    }
    __syncthreads();                  // all waves done reading mT

    // ---- epilogue: block reduce via LDS (reuse mT), then replicated atomics ----
    float* red  = (float*)mT;        // [4 waves][32 bins][10 cls] = 1280 floats
    float* redN = red + 1280;        // [4 waves][10]

    f32x4 d1 = accH1 + accL1;
    f32x4 d2 = accH2 + accL2;
    if (n15 < NCLS) {
        #pragma unroll
        for (int r = 0; r < 4; ++r) {
            int b1 = g * 4 + r;                  // C/D: row=(lane>>4)*4+reg, col=lane&15
            red[(w * 32 + b1) * NCLS + n15]      = d1[r];
            red[(w * 32 + 16 + b1) * NCLS + n15] = d2[r];
        }
    }
    if (lane < NCLS) redN[w * NCLS + lane] = cnt[0];   // row 0 of count tile
    __syncthreads();

    const int rep = chunk & (NREP - 1);       // XCD-aligned (chunk%8 == XCD id)
    float* gDr = gD + rep * (NBINS * NCLS);
    float* gNr = gN + rep * (2 * NCLS);
    const int nsel = (chunk < chunksPerN) ? 0 : 1;

    for (int i = tid; i < NBINS * NCLS; i += 256) {
        float s = red[i] + red[320 + i] + red[640 + i] + red[960 + i];
        atomicAdd(&gDr[i], s);
    }
    if (tid < NCLS) {
        float s = redN[tid] + redN[10 + tid] + redN[20 + tid] + redN[30 + tid];
        atomicAdd(&gNr[nsel * NCLS + tid], s);
    }
}

__global__ __launch_bounds__(512) void dvh_final(
    const float* __restrict__ gD, const float* __restrict__ gN, float* __restrict__ out)
{
    __shared__ float red[512];
    __shared__ float nvs[2 * NCLS];
    const int t = threadIdx.x;

    if (t < 2 * NCLS) {
        float s = 1.f;
        #pragma unroll
        for (int r = 0; r < NREP; ++r) s += gN[r * (2 * NCLS) + t];
        nvs[t] = s;
    }
    float d = 0.f;
    if (t < NBINS * NCLS) {
        #pragma unroll
        for (int r = 0; r < NREP; ++r) d += gD[r * (NBINS * NCLS) + t];
    }
    __syncthreads();

    float v = 0.f;
    if (t < NBINS * NCLS) {
        int c = t % NCLS;
        float nv0 = nvs[c], nv1 = nvs[NCLS + c];
        v = d * d * (1.f / (nv0 * nv0) + 1.f / (nv1 * nv1));
    }
    red[t] = v;
    __syncthreads();
    for (int s = 256; s > 0; s >>= 1) {
        if (t < s) red[t] += red[t + s];
        __syncthreads();
    }
    if (t == 0) out[0] = red[0] * (1.f / 1280.f);
}

extern "C" void kernel_launch(void* const* d_in, const int* in_sizes, int n_in,
                              void* d_out, int out_size, void* d_ws, size_t ws_size,
                              hipStream_t stream) {
    const float* pred = (const float*)d_in[0];
    const float* targ = (const float*)d_in[1];
    const float* mask = (const float*)d_in[2];
    float* gD = (float*)d_ws;                                    // NREP x 320 floats
    float* gN = (float*)((char*)d_ws + NREP * NBINS * NCLS * 4); // NREP x 20 floats

    hipMemsetAsync(d_ws, 0, NREP * (NBINS * NCLS + 2 * NCLS) * 4, stream);

    int totalVox    = in_sizes[0];           // N*V = 4194304
    int chunksTotal = totalVox / CHUNK;      // 8192
    int chunksPerN  = chunksTotal / 2;       // 4096

    dvh_main<<<chunksTotal, 256, 0, stream>>>(pred, targ, mask, gD, gN, chunksPerN);
    dvh_final<<<1, 512, 0, stream>>>(gD, gN, (float*)d_out);
}

// Round 14
// 53.967 us; speedup vs baseline: 3.5336x; 1.1034x over previous
//
#include <hip/hip_runtime.h>

typedef __attribute__((ext_vector_type(8))) short short8;   // 8 bf16 (4 VGPR)
typedef __attribute__((ext_vector_type(4))) float f32x4;    // MFMA C/D
typedef __attribute__((ext_vector_type(4))) int int4v;

#define CHUNK 512
#define NBINS 32
#define NCLS  10
#define NREP  8

__global__ __launch_bounds__(256) void dvh_main(
    const float* __restrict__ pred, const float* __restrict__ targ,
    const float* __restrict__ mask, float* __restrict__ gD, float* __restrict__ gN,
    int chunksPerN)
{
    __shared__ float2 sE[CHUNK];                 // (Ep,Et) per voxel, 4 KB
    __shared__ unsigned short mT[16 * 512];      // bf16 masks [cls][vox] swizzled, 16 KB

    const int tid  = threadIdx.x;
    const int lane = tid & 63;
    const int w    = tid >> 6;       // wave 0..3
    const int n15  = lane & 15;      // MFMA row/col index
    const int g    = lane >> 4;      // k-group 0..3

    const int chunk = blockIdx.x;
    const size_t vbase = (size_t)chunk * CHUNK;

    // ---- issue ALL global loads first (latency hides under setup) ----
    float2 p = ((const float2*)(pred + vbase))[tid];
    float2 t = ((const float2*)(targ + vbase))[tid];
    uint4 mv[5];
    {
        const uint4* m4g = (const uint4*)(mask + vbase * NCLS);
        #pragma unroll
        for (int k = 0; k < 5; ++k) mv[k] = m4g[k * 256 + tid];
    }

    // mT class rows 10..15 intentionally uninitialized: garbage feeds only
    // MFMA output columns n=10..15, which are never read.

    const float K1 = __expf((float)n15);        // e^bin, bins 0..15
    const float K2 = K1 * 8886110.5f;           // * e^16 -> bins 16..31

    // ---- stage doses: exp once per voxel ----
    *(float4*)&sE[2 * tid] = make_float4(__expf(-32.f * p.x), __expf(-32.f * t.x),
                                         __expf(-32.f * p.y), __expf(-32.f * t.y));
    // ---- stage masks: 0/1 f32 -> bf16 (top 16 bits), swizzled transpose ----
    // incremental (v,c) addressing: one div total, +1 steps with wrap; k-step
    // jumps f by +1021 = 102*10 + 1 -> v += 102 then a normal +1 step.
    {
        int f0 = tid * 4;
        int vv = f0 / 10;
        int cc = f0 - vv * 10;
        #pragma unroll
        for (int k = 0; k < 5; ++k) {
            unsigned int e[4] = {mv[k].x, mv[k].y, mv[k].z, mv[k].w};
            #pragma unroll
            for (int q = 0; q < 4; ++q) {
                mT[cc * 512 + (((vv >> 3) ^ (cc & 7)) << 3) + (vv & 7)] =
                    (unsigned short)(e[q] >> 16);
                cc += 1;
                int wrap = (cc >= 10);
                cc -= wrap * 10;
                vv += wrap;
            }
            vv += 102;   // k-boundary: remaining +1020 of the +1024 jump
        }
    }
    __syncthreads();

    f32x4 acc1 = {0,0,0,0};          // bins 0-15
    f32x4 acc2 = {0,0,0,0};          // bins 16-31
    f32x4 cnt  = {0,0,0,0};          // voxel counts
    short8 ones;
    #pragma unroll
    for (int i = 0; i < 8; ++i) ones[i] = (short)0x3F80;   // bf16 1.0

    #pragma unroll
    for (int st = 0; st < 4; ++st) {
        const int vb = (w * 4 + st) * 32;    // this wave's 32-voxel K-block
        const int v0 = vb + g * 8;           // this lane's 8 voxels
        short8 fb = *(const short8*)&mT[n15 * 512 + (((v0 >> 3) ^ (n15 & 7)) << 3)];
        const float4* e4 = (const float4*)&sE[v0];

        int u1[4], u2[4];
        #pragma unroll
        for (int j = 0; j < 4; ++j) {
            float4 q = e4[j];                 // vox a: (q.x,q.y)  vox b: (q.z,q.w)
            float dea = q.y - q.x, deb = q.w - q.z;
            // K1: sig_p - sig_t for 2 voxels, round-nearest bf16 pack
            float pa = fmaf(q.x, K1, 1.f) * fmaf(q.y, K1, 1.f);
            float pb = fmaf(q.z, K1, 1.f) * fmaf(q.w, K1, 1.f);
            float sa = dea * K1 * __builtin_amdgcn_rcpf(pa);
            float sb = deb * K1 * __builtin_amdgcn_rcpf(pb);
            unsigned h1;
            asm("v_cvt_pk_bf16_f32 %0, %1, %2" : "=v"(h1) : "v"(sa), "v"(sb));
            u1[j] = (int)h1;
            // K2
            float pc = fmaf(q.x, K2, 1.f) * fmaf(q.y, K2, 1.f);
            float pd = fmaf(q.z, K2, 1.f) * fmaf(q.w, K2, 1.f);
            float sc = dea * K2 * __builtin_amdgcn_rcpf(pc);
            float sd = deb * K2 * __builtin_amdgcn_rcpf(pd);
            unsigned h2;
            asm("v_cvt_pk_bf16_f32 %0, %1, %2" : "=v"(h2) : "v"(sc), "v"(sd));
            u2[j] = (int)h2;
        }
        int4v t1 = {u1[0], u1[1], u1[2], u1[3]};
        int4v t2 = {u2[0], u2[1], u2[2], u2[3]};
        short8 A1 = __builtin_bit_cast(short8, t1);
        short8 A2 = __builtin_bit_cast(short8, t2);

        acc1 = __builtin_amdgcn_mfma_f32_16x16x32_bf16(A1, fb, acc1, 0, 0, 0);
        acc2 = __builtin_amdgcn_mfma_f32_16x16x32_bf16(A2, fb, acc2, 0, 0, 0);
        cnt  = __builtin_amdgcn_mfma_f32_16x16x32_bf16(ones, fb, cnt, 0, 0, 0);
    }
    __syncthreads();                  // all waves done reading mT

    // ---- epilogue: block reduce via LDS (reuse mT), then replicated atomics ----
    float* red  = (float*)mT;        // [4 waves][32 bins][10 cls] = 1280 floats
    float* redN = red + 1280;        // [4 waves][10]

    if (n15 < NCLS) {
        #pragma unroll
        for (int r = 0; r < 4; ++r) {
            int b1 = g * 4 + r;                  // C/D: row=(lane>>4)*4+reg, col=lane&15
            red[(w * 32 + b1) * NCLS + n15]      = acc1[r];
            red[(w * 32 + 16 + b1) * NCLS + n15] = acc2[r];
        }
    }
    if (lane < NCLS) redN[w * NCLS + lane] = cnt[0];   // row 0 of count tile
    __syncthreads();

    const int rep = chunk & (NREP - 1);
    float* gDr = gD + rep * (NBINS * NCLS);
    float* gNr = gN + rep * (2 * NCLS);
    const int nsel = (chunk < chunksPerN) ? 0 : 1;

    for (int i = tid; i < NBINS * NCLS; i += 256) {
        float s = red[i] + red[320 + i] + red[640 + i] + red[960 + i];
        atomicAdd(&gDr[i], s);
    }
    if (tid < NCLS) {
        float s = redN[tid] + redN[10 + tid] + redN[20 + tid] + redN[30 + tid];
        atomicAdd(&gNr[nsel * NCLS + tid], s);
    }
}

__global__ __launch_bounds__(512) void dvh_final(
    const float* __restrict__ gD, const float* __restrict__ gN, float* __restrict__ out)
{
    __shared__ float red[512];
    __shared__ float nvs[2 * NCLS];
    const int t = threadIdx.x;

    if (t < 2 * NCLS) {
        float s = 1.f;
        #pragma unroll
        for (int r = 0; r < NREP; ++r) s += gN[r * (2 * NCLS) + t];
        nvs[t] = s;
    }
    float d = 0.f;
    if (t < NBINS * NCLS) {
        #pragma unroll
        for (int r = 0; r < NREP; ++r) d += gD[r * (NBINS * NCLS) + t];
    }
    __syncthreads();

    float v = 0.f;
    if (t < NBINS * NCLS) {
        int c = t % NCLS;
        float nv0 = nvs[c], nv1 = nvs[NCLS + c];
        v = d * d * (1.f / (nv0 * nv0) + 1.f / (nv1 * nv1));
    }
    red[t] = v;
    __syncthreads();
    for (int s = 256; s > 0; s >>= 1) {
        if (t < s) red[t] += red[t + s];
        __syncthreads();
    }
    if (t == 0) out[0] = red[0] * (1.f / 1280.f);
}

extern "C" void kernel_launch(void* const* d_in, const int* in_sizes, int n_in,
                              void* d_out, int out_size, void* d_ws, size_t ws_size,
                              hipStream_t stream) {
    const float* pred = (const float*)d_in[0];
    const float* targ = (const float*)d_in[1];
    const float* mask = (const float*)d_in[2];
    float* gD = (float*)d_ws;                                    // NREP x 320 floats
    float* gN = (float*)((char*)d_ws + NREP * NBINS * NCLS * 4); // NREP x 20 floats

    hipMemsetAsync(d_ws, 0, NREP * (NBINS * NCLS + 2 * NCLS) * 4, stream);

    int totalVox    = in_sizes[0];           // N*V = 4194304
    int chunksTotal = totalVox / CHUNK;      // 8192
    int chunksPerN  = chunksTotal / 2;       // 4096

    dvh_main<<<chunksTotal, 256, 0, stream>>>(pred, targ, mask, gD, gN, chunksPerN);
    dvh_final<<<1, 512, 0, stream>>>(gD, gN, (float*)d_out);
}

// Round 15
// 50.787 us; speedup vs baseline: 3.7548x; 1.0626x over previous
//
#include <hip/hip_runtime.h>

typedef __attribute__((ext_vector_type(8))) short short8;   // 8 bf16 (4 VGPR)
typedef __attribute__((ext_vector_type(4))) float f32x4;    // MFMA C/D
typedef __attribute__((ext_vector_type(4))) int int4v;

#define CHUNK 1024
#define NBINS 32
#define NCLS  10
#define NREP  8

__global__ __launch_bounds__(256) void dvh_main(
    const float* __restrict__ pred, const float* __restrict__ targ,
    const float* __restrict__ mask, float* __restrict__ gD, float* __restrict__ gN,
    int chunksPerN)
{
    __shared__ float2 sE[CHUNK];                 // (Ep,Et) per voxel, 8 KB
    __shared__ unsigned short mT[16 * CHUNK];    // bf16 masks [cls][vox] swizzled, 32 KB

    const int tid  = threadIdx.x;
    const int lane = tid & 63;
    const int w    = tid >> 6;       // wave 0..3
    const int n15  = lane & 15;      // MFMA row/col index
    const int g    = lane >> 4;      // k-group 0..3

    const int chunk = blockIdx.x;
    const size_t vbase = (size_t)chunk * CHUNK;

    // ---- issue ALL global loads first (latency overlaps across blocks) ----
    float4 p = ((const float4*)(pred + vbase))[tid];     // voxels 4t..4t+3
    float4 t = ((const float4*)(targ + vbase))[tid];
    uint4 mv[10];
    {
        const uint4* m4g = (const uint4*)(mask + vbase * NCLS);
        #pragma unroll
        for (int k = 0; k < 10; ++k) mv[k] = m4g[k * 256 + tid];
    }

    // mT class rows 10..15 intentionally uninitialized: garbage feeds only
    // MFMA output columns n=10..15, which are never read.

    const float K1 = __expf((float)n15);        // e^bin, bins 0..15
    const float K2 = K1 * 8886110.5f;           // * e^16 -> bins 16..31

    // ---- stage doses: exp once per voxel ----
    *(float4*)&sE[4 * tid]     = make_float4(__expf(-32.f * p.x), __expf(-32.f * t.x),
                                             __expf(-32.f * p.y), __expf(-32.f * t.y));
    *(float4*)&sE[4 * tid + 2] = make_float4(__expf(-32.f * p.z), __expf(-32.f * t.z),
                                             __expf(-32.f * p.w), __expf(-32.f * t.w));
    // ---- stage masks: 0/1 f32 -> bf16 (top 16 bits), swizzled transpose ----
    // incremental (v,c): one div total; k-stride = 1024 floats = 102*10+4,
    // so after the 4 q-steps (+4 with wraps) add vv += 102.
    {
        int f0 = tid * 4;
        int vv = f0 / 10;
        int cc = f0 - vv * 10;
        #pragma unroll
        for (int k = 0; k < 10; ++k) {
            unsigned int e[4] = {mv[k].x, mv[k].y, mv[k].z, mv[k].w};
            #pragma unroll
            for (int q = 0; q < 4; ++q) {
                mT[cc * CHUNK + (((vv >> 3) ^ (cc & 7)) << 3) + (vv & 7)] =
                    (unsigned short)(e[q] >> 16);
                cc += 1;
                int wrap = (cc >= 10);
                cc -= wrap * 10;
                vv += wrap;
            }
            vv += 102;
        }
    }
    __syncthreads();

    f32x4 acc1 = {0,0,0,0};          // bins 0-15
    f32x4 acc2 = {0,0,0,0};          // bins 16-31
    f32x4 cnt  = {0,0,0,0};          // voxel counts
    short8 ones;
    #pragma unroll
    for (int i = 0; i < 8; ++i) ones[i] = (short)0x3F80;   // bf16 1.0

    #pragma unroll
    for (int st = 0; st < 8; ++st) {
        const int vb = (w * 8 + st) * 32;    // this wave's 32-voxel K-block
        const int v0 = vb + g * 8;           // this lane's 8 voxels
        short8 fb = *(const short8*)&mT[n15 * CHUNK + (((v0 >> 3) ^ (n15 & 7)) << 3)];
        const float4* e4 = (const float4*)&sE[v0];

        int u1[4], u2[4];
        #pragma unroll
        for (int j = 0; j < 4; ++j) {
            float4 q = e4[j];                 // vox a: (q.x,q.y)  vox b: (q.z,q.w)
            float dea = q.y - q.x, deb = q.w - q.z;
            float pa = fmaf(q.x, K1, 1.f) * fmaf(q.y, K1, 1.f);
            float pb = fmaf(q.z, K1, 1.f) * fmaf(q.w, K1, 1.f);
            float sa = dea * K1 * __builtin_amdgcn_rcpf(pa);
            float sb = deb * K1 * __builtin_amdgcn_rcpf(pb);
            unsigned h1;
            asm("v_cvt_pk_bf16_f32 %0, %1, %2" : "=v"(h1) : "v"(sa), "v"(sb));
            u1[j] = (int)h1;
            float pc = fmaf(q.x, K2, 1.f) * fmaf(q.y, K2, 1.f);
            float pd = fmaf(q.z, K2, 1.f) * fmaf(q.w, K2, 1.f);
            float sc = dea * K2 * __builtin_amdgcn_rcpf(pc);
            float sd = deb * K2 * __builtin_amdgcn_rcpf(pd);
            unsigned h2;
            asm("v_cvt_pk_bf16_f32 %0, %1, %2" : "=v"(h2) : "v"(sc), "v"(sd));
            u2[j] = (int)h2;
        }
        int4v t1 = {u1[0], u1[1], u1[2], u1[3]};
        int4v t2 = {u2[0], u2[1], u2[2], u2[3]};
        short8 A1 = __builtin_bit_cast(short8, t1);
        short8 A2 = __builtin_bit_cast(short8, t2);

        acc1 = __builtin_amdgcn_mfma_f32_16x16x32_bf16(A1, fb, acc1, 0, 0, 0);
        acc2 = __builtin_amdgcn_mfma_f32_16x16x32_bf16(A2, fb, acc2, 0, 0, 0);
        cnt  = __builtin_amdgcn_mfma_f32_16x16x32_bf16(ones, fb, cnt, 0, 0, 0);
    }
    __syncthreads();                  // all waves done reading mT

    // ---- epilogue: block reduce via LDS (reuse mT), then replicated atomics ----
    float* red  = (float*)mT;        // [4 waves][32 bins][10 cls] = 1280 floats
    float* redN = red + 1280;        // [4 waves][10]

    if (n15 < NCLS) {
        #pragma unroll
        for (int r = 0; r < 4; ++r) {
            int b1 = g * 4 + r;                  // C/D: row=(lane>>4)*4+reg, col=lane&15
            red[(w * 32 + b1) * NCLS + n15]      = acc1[r];
            red[(w * 32 + 16 + b1) * NCLS + n15] = acc2[r];
        }
    }
    if (lane < NCLS) redN[w * NCLS + lane] = cnt[0];   // row 0 of count tile
    __syncthreads();

    const int rep = chunk & (NREP - 1);
    float* gDr = gD + rep * (NBINS * NCLS);
    float* gNr = gN + rep * (2 * NCLS);
    const int nsel = (chunk < chunksPerN) ? 0 : 1;

    for (int i = tid; i < NBINS * NCLS; i += 256) {
        float s = red[i] + red[320 + i] + red[640 + i] + red[960 + i];
        atomicAdd(&gDr[i], s);
    }
    if (tid < NCLS) {
        float s = redN[tid] + redN[10 + tid] + redN[20 + tid] + redN[30 + tid];
        atomicAdd(&gNr[nsel * NCLS + tid], s);
    }
}

__global__ __launch_bounds__(512) void dvh_final(
    const float* __restrict__ gD, const float* __restrict__ gN, float* __restrict__ out)
{
    __shared__ float red[512];
    __shared__ float nvs[2 * NCLS];
    const int t = threadIdx.x;

    if (t < 2 * NCLS) {
        float s = 1.f;
        #pragma unroll
        for (int r = 0; r < NREP; ++r) s += gN[r * (2 * NCLS) + t];
        nvs[t] = s;
    }
    float d = 0.f;
    if (t < NBINS * NCLS) {
        #pragma unroll
        for (int r = 0; r < NREP; ++r) d += gD[r * (NBINS * NCLS) + t];
    }
    __syncthreads();

    float v = 0.f;
    if (t < NBINS * NCLS) {
        int c = t % NCLS;
        float nv0 = nvs[c], nv1 = nvs[NCLS + c];
        v = d * d * (1.f / (nv0 * nv0) + 1.f / (nv1 * nv1));
    }
    red[t] = v;
    __syncthreads();
    for (int s = 256; s > 0; s >>= 1) {
        if (t < s) red[t] += red[t + s];
        __syncthreads();
    }
    if (t == 0) out[0] = red[0] * (1.f / 1280.f);
}

extern "C" void kernel_launch(void* const* d_in, const int* in_sizes, int n_in,
                              void* d_out, int out_size, void* d_ws, size_t ws_size,
                              hipStream_t stream) {
    const float* pred = (const float*)d_in[0];
    const float* targ = (const float*)d_in[1];
    const float* mask = (const float*)d_in[2];
    float* gD = (float*)d_ws;                                    // NREP x 320 floats
    float* gN = (float*)((char*)d_ws + NREP * NBINS * NCLS * 4); // NREP x 20 floats

    hipMemsetAsync(d_ws, 0, NREP * (NBINS * NCLS + 2 * NCLS) * 4, stream);

    int totalVox    = in_sizes[0];           // N*V = 4194304
    int chunksTotal = totalVox / CHUNK;      // 4096
    int chunksPerN  = chunksTotal / 2;       // 2048

    dvh_main<<<chunksTotal, 256, 0, stream>>>(pred, targ, mask, gD, gN, chunksPerN);
    dvh_final<<<1, 512, 0, stream>>>(gD, gN, (float*)d_out);
}

// Round 16
// 50.098 us; speedup vs baseline: 3.8064x; 1.0137x over previous
//
#include <hip/hip_runtime.h>

typedef __attribute__((ext_vector_type(8))) short short8;   // 8 bf16 (4 VGPR)
typedef __attribute__((ext_vector_type(4))) float f32x4;    // MFMA C/D
typedef __attribute__((ext_vector_type(4))) int int4v;

#define CHUNK 1024
#define NBINS 32
#define NCLS  10
#define NREP  8

__global__ __launch_bounds__(256) void dvh_main(
    const float* __restrict__ pred, const float* __restrict__ targ,
    const float* __restrict__ mask, float* __restrict__ gD, float* __restrict__ gN,
    int chunksPerN)
{
    __shared__ float2 sE[CHUNK];                 // (Ep,Et) per voxel, 8 KB
    __shared__ unsigned short mT[NCLS * CHUNK];  // bf16 masks [10][1024] swizzled, 20 KB
    // total 28 KB -> 5 blocks/CU (was 40 KB -> 4)

    const int tid  = threadIdx.x;
    const int lane = tid & 63;
    const int w    = tid >> 6;       // wave 0..3
    const int n15  = lane & 15;      // MFMA row/col index
    const int g    = lane >> 4;      // k-group 0..3

    const int chunk = blockIdx.x;
    const size_t vbase = (size_t)chunk * CHUNK;

    // ---- issue ALL global loads first (latency overlaps across blocks) ----
    float4 p = ((const float4*)(pred + vbase))[tid];     // voxels 4t..4t+3
    float4 t = ((const float4*)(targ + vbase))[tid];
    uint4 mv[10];
    {
        const uint4* m4g = (const uint4*)(mask + vbase * NCLS);
        #pragma unroll
        for (int k = 0; k < 10; ++k) mv[k] = m4g[k * 256 + tid];
    }

    const float K1 = __expf((float)n15);        // e^bin, bins 0..15
    const float K2 = K1 * 8886110.5f;           // * e^16 -> bins 16..31

    // ---- stage doses: exp once per voxel ----
    *(float4*)&sE[4 * tid]     = make_float4(__expf(-32.f * p.x), __expf(-32.f * t.x),
                                             __expf(-32.f * p.y), __expf(-32.f * t.y));
    *(float4*)&sE[4 * tid + 2] = make_float4(__expf(-32.f * p.z), __expf(-32.f * t.z),
                                             __expf(-32.f * p.w), __expf(-32.f * t.w));
    // ---- stage masks: 0/1 f32 -> bf16 (top 16 bits), swizzled transpose ----
    {
        int f0 = tid * 4;
        int vv = f0 / 10;
        int cc = f0 - vv * 10;
        #pragma unroll
        for (int k = 0; k < 10; ++k) {
            unsigned int e[4] = {mv[k].x, mv[k].y, mv[k].z, mv[k].w};
            #pragma unroll
            for (int q = 0; q < 4; ++q) {
                mT[cc * CHUNK + (((vv >> 3) ^ (cc & 7)) << 3) + (vv & 7)] =
                    (unsigned short)(e[q] >> 16);
                cc += 1;
                int wrap = (cc >= 10);
                cc -= wrap * 10;
                vv += wrap;
            }
            vv += 102;   // k-stride 1024 floats = 102*10 + 4
        }
    }
    __syncthreads();

    f32x4 acc1 = {0,0,0,0};          // bins 0-15
    f32x4 acc2 = {0,0,0,0};          // bins 16-31
    f32x4 cnt  = {0,0,0,0};          // voxel counts
    short8 ones;
    #pragma unroll
    for (int i = 0; i < 8; ++i) ones[i] = (short)0x3F80;   // bf16 1.0

    // B-row: lanes n15>=10 have no class; read row n15-10 (junk-but-valid,
    // feeds only MFMA output columns 10..15, which are never consumed).
    const int brow = (n15 < NCLS) ? n15 : (n15 - NCLS);

    #pragma unroll
    for (int st = 0; st < 8; ++st) {
        const int vb = (w * 8 + st) * 32;    // this wave's 32-voxel K-block
        const int v0 = vb + g * 8;           // this lane's 8 voxels
        short8 fb = *(const short8*)&mT[brow * CHUNK + (((v0 >> 3) ^ (brow & 7)) << 3)];
        const float4* e4 = (const float4*)&sE[v0];

        int u1[4], u2[4];
        #pragma unroll
        for (int j = 0; j < 4; ++j) {
            float4 q = e4[j];                 // vox a: (q.x,q.y)  vox b: (q.z,q.w)
            float dea = q.y - q.x, deb = q.w - q.z;
            float pa = fmaf(q.x, K1, 1.f) * fmaf(q.y, K1, 1.f);
            float pb = fmaf(q.z, K1, 1.f) * fmaf(q.w, K1, 1.f);
            float sa = dea * K1 * __builtin_amdgcn_rcpf(pa);
            float sb = deb * K1 * __builtin_amdgcn_rcpf(pb);
            unsigned h1;
            asm("v_cvt_pk_bf16_f32 %0, %1, %2" : "=v"(h1) : "v"(sa), "v"(sb));
            u1[j] = (int)h1;
            float pc = fmaf(q.x, K2, 1.f) * fmaf(q.y, K2, 1.f);
            float pd = fmaf(q.z, K2, 1.f) * fmaf(q.w, K2, 1.f);
            float sc = dea * K2 * __builtin_amdgcn_rcpf(pc);
            float sd = deb * K2 * __builtin_amdgcn_rcpf(pd);
            unsigned h2;
            asm("v_cvt_pk_bf16_f32 %0, %1, %2" : "=v"(h2) : "v"(sc), "v"(sd));
            u2[j] = (int)h2;
        }
        int4v t1 = {u1[0], u1[1], u1[2], u1[3]};
        int4v t2 = {u2[0], u2[1], u2[2], u2[3]};
        short8 A1 = __builtin_bit_cast(short8, t1);
        short8 A2 = __builtin_bit_cast(short8, t2);

        acc1 = __builtin_amdgcn_mfma_f32_16x16x32_bf16(A1, fb, acc1, 0, 0, 0);
        acc2 = __builtin_amdgcn_mfma_f32_16x16x32_bf16(A2, fb, acc2, 0, 0, 0);
        cnt  = __builtin_amdgcn_mfma_f32_16x16x32_bf16(ones, fb, cnt, 0, 0, 0);
    }
    __syncthreads();                  // all waves done reading mT

    // ---- epilogue: block reduce via LDS (reuse mT), then replicated atomics ----
    float* red  = (float*)mT;        // [4 waves][32 bins][10 cls] = 1280 floats (5 KB)
    float* redN = red + 1280;        // [4 waves][10]

    if (n15 < NCLS) {
        #pragma unroll
        for (int r = 0; r < 4; ++r) {
            int b1 = g * 4 + r;                  // C/D: row=(lane>>4)*4+reg, col=lane&15
            red[(w * 32 + b1) * NCLS + n15]      = acc1[r];
            red[(w * 32 + 16 + b1) * NCLS + n15] = acc2[r];
        }
    }
    if (lane < NCLS) redN[w * NCLS + lane] = cnt[0];   // row 0 of count tile
    __syncthreads();

    const int rep = chunk & (NREP - 1);
    float* gDr = gD + rep * (NBINS * NCLS);
    float* gNr = gN + rep * (2 * NCLS);
    const int nsel = (chunk < chunksPerN) ? 0 : 1;

    for (int i = tid; i < NBINS * NCLS; i += 256) {
        float s = red[i] + red[320 + i] + red[640 + i] + red[960 + i];
        atomicAdd(&gDr[i], s);
    }
    if (tid < NCLS) {
        float s = redN[tid] + redN[10 + tid] + redN[20 + tid] + redN[30 + tid];
        atomicAdd(&gNr[nsel * NCLS + tid], s);
    }
}

__global__ __launch_bounds__(512) void dvh_final(
    const float* __restrict__ gD, const float* __restrict__ gN, float* __restrict__ out)
{
    __shared__ float red[512];
    __shared__ float nvs[2 * NCLS];
    const int t = threadIdx.x;

    if (t < 2 * NCLS) {
        float s = 1.f;
        #pragma unroll
        for (int r = 0; r < NREP; ++r) s += gN[r * (2 * NCLS) + t];
        nvs[t] = s;
    }
    float d = 0.f;
    if (t < NBINS * NCLS) {
        #pragma unroll
        for (int r = 0; r < NREP; ++r) d += gD[r * (NBINS * NCLS) + t];
    }
    __syncthreads();

    float v = 0.f;
    if (t < NBINS * NCLS) {
        int c = t % NCLS;
        float nv0 = nvs[c], nv1 = nvs[NCLS + c];
        v = d * d * (1.f / (nv0 * nv0) + 1.f / (nv1 * nv1));
    }
    red[t] = v;
    __syncthreads();
    for (int s = 256; s > 0; s >>= 1) {
        if (t < s) red[t] += red[t + s];
        __syncthreads();
    }
    if (t == 0) out[0] = red[0] * (1.f / 1280.f);
}

extern "C" void kernel_launch(void* const* d_in, const int* in_sizes, int n_in,
                              void* d_out, int out_size, void* d_ws, size_t ws_size,
                              hipStream_t stream) {
    const float* pred = (const float*)d_in[0];
    const float* targ = (const float*)d_in[1];
    const float* mask = (const float*)d_in[2];
    float* gD = (float*)d_ws;                                    // NREP x 320 floats
    float* gN = (float*)((char*)d_ws + NREP * NBINS * NCLS * 4); // NREP x 20 floats

    hipMemsetAsync(d_ws, 0, NREP * (NBINS * NCLS + 2 * NCLS) * 4, stream);

    int totalVox    = in_sizes[0];           // N*V = 4194304
    int chunksTotal = totalVox / CHUNK;      // 4096
    int chunksPerN  = chunksTotal / 2;       // 2048

    dvh_main<<<chunksTotal, 256, 0, stream>>>(pred, targ, mask, gD, gN, chunksPerN);
    dvh_final<<<1, 512, 0, stream>>>(gD, gN, (float*)d_out);
}